// Round 8
// baseline (4200.815 us; speedup 1.0000x reference)
//
#include <hip/hip_runtime.h>
#include <math.h>

// Problem constants
#define BB 64
#define TT 512
#define II 512
#define HH 1024
#define OO 128
#define GN (3*HH)       // 3072
#define TC 64           // time chunk
#define NCH (TT/TC)     // 8 chunks
#define NSLOT 65        // rolling h slots; 65 odd => parity(t) != parity(t-65)

using u16 = unsigned short;
typedef __attribute__((ext_vector_type(8))) short bf16x8;
typedef __attribute__((ext_vector_type(4))) float f32x4;
typedef __attribute__((ext_vector_type(4))) unsigned short u16x4;
typedef __attribute__((ext_vector_type(2))) unsigned long long u64x2;

#define PARMASK64 0x0001000100010001ULL
#define KEEPMASK64 0xFFFEFFFEFFFEFFFEULL

__device__ __forceinline__ u16 f2bf(float f){
  unsigned u = __builtin_bit_cast(unsigned, f);
  u += 0x7fffu + ((u >> 16) & 1u);          // RNE
  return (u16)(u >> 16);
}
__device__ __forceinline__ float bf2f(u16 h){
  unsigned u = ((unsigned)h) << 16;
  return __builtin_bit_cast(float, u);
}

// ---------------------------------------------------------------- f32 -> bf16
__global__ __launch_bounds__(256) void cvt_kernel(const float* __restrict__ s,
                                                  u16* __restrict__ d, int n4){
  int stride = gridDim.x * 256;
  for (int i = blockIdx.x * 256 + threadIdx.x; i < n4; i += stride){
    float4 v = reinterpret_cast<const float4*>(s)[i];
    u16x4 o; o.x = f2bf(v.x); o.y = f2bf(v.y); o.z = f2bf(v.z); o.w = f2bf(v.w);
    reinterpret_cast<u16x4*>(d)[i] = o;
  }
}

// ---------------- hbuf slot init: slot s gets parity opposite of its first
// writer (step t=s writes parity s&1 -> init = (s&1)^1). ATOMIC stores so the
// pattern reaches the LLC (plain stores could linger in a write-back L2 and
// leave stale run-1 data visible to uncached polls on graph replay).
__global__ __launch_bounds__(256) void hinit_kernel(unsigned long long* hb0,
                                                    unsigned long long* hb1){
  const int wper = BB * HH / 4;                  // u64 words per slot = 16384
  int stride = gridDim.x * 256;
  for (int i = blockIdx.x * 256 + threadIdx.x; i < NSLOT * wper; i += stride){
    int s = i / wper;
    unsigned long long v = ((s & 1) ^ 1) ? PARMASK64 : 0ULL;
    __hip_atomic_store(hb0 + i, v, __ATOMIC_RELAXED, __HIP_MEMORY_SCOPE_AGENT);
    __hip_atomic_store(hb1 + i, v, __ATOMIC_RELAXED, __HIP_MEMORY_SCOPE_AGENT);
  }
}

// --------------------------------------------- x chunk gather+convert to bf16
__global__ __launch_bounds__(256) void cvtx_chunk(const float* __restrict__ x,
                                                  u16* __restrict__ d, int t0){
  const int per_b = TC * II / 4;
  int stride = gridDim.x * 256;
  for (int i = blockIdx.x * 256 + threadIdx.x; i < BB * per_b; i += stride){
    int b = i / per_b, r = i - b * per_b;
    float4 v = reinterpret_cast<const float4*>(x)[(size_t)(b * TT + t0) * (II/4) + r];
    u16x4 o; o.x = f2bf(v.x); o.y = f2bf(v.y); o.z = f2bf(v.z); o.w = f2bf(v.w);
    reinterpret_cast<u16x4*>(d)[(size_t)b * per_b + r] = o;
  }
}

// ------------------------------------------------- bf16 GEMM: C = A@Bw^T + bias
// m97 structure: 128x128 tile, BK=32, 4 waves, global_load_lds width 16.
template<int K>
__global__ __launch_bounds__(256) void gemm_bias(const u16* __restrict__ A,
    const u16* __restrict__ Bw, const float* __restrict__ bias, u16* __restrict__ C){
  __shared__ u16 As[128*32];
  __shared__ u16 Bs[128*32];
  int tid = threadIdx.x;
  int lane = tid & 63, wave = tid >> 6;
  int m0 = blockIdx.x * 128, n0 = blockIdx.y * 128;
  int wr = (wave >> 1) * 64, wc = (wave & 1) * 64;
  int fr = lane & 15, fo = (lane >> 4) * 8;
  f32x4 acc[4][4] = {};
  for (int k0 = 0; k0 < K; k0 += 32){
    __syncthreads();
    #pragma unroll
    for (int c = 0; c < 2; ++c){
      int chunk = wave * 2 + c;
      int s = chunk * 64 + lane;
      int row = s >> 2, o = s & 3;
      const u16* ga = A  + (size_t)(m0 + row) * K + k0 + o * 8;
      const u16* gb = Bw + (size_t)(n0 + row) * K + k0 + o * 8;
      __builtin_amdgcn_global_load_lds(
          (const __attribute__((address_space(1))) unsigned int*)ga,
          (__attribute__((address_space(3))) unsigned int*)(As + chunk * 512), 16, 0, 0);
      __builtin_amdgcn_global_load_lds(
          (const __attribute__((address_space(1))) unsigned int*)gb,
          (__attribute__((address_space(3))) unsigned int*)(Bs + chunk * 512), 16, 0, 0);
    }
    __syncthreads();
    bf16x8 af[4], bf[4];
    #pragma unroll
    for (int m = 0; m < 4; ++m)
      af[m] = *reinterpret_cast<const bf16x8*>(&As[(wr + m*16 + fr) * 32 + fo]);
    #pragma unroll
    for (int n = 0; n < 4; ++n)
      bf[n] = *reinterpret_cast<const bf16x8*>(&Bs[(wc + n*16 + fr) * 32 + fo]);
    #pragma unroll
    for (int m = 0; m < 4; ++m)
      #pragma unroll
      for (int n = 0; n < 4; ++n)
        acc[m][n] = __builtin_amdgcn_mfma_f32_16x16x32_bf16(af[m], bf[n], acc[m][n], 0, 0, 0);
  }
  int r4 = (lane >> 4) * 4;
  #pragma unroll
  for (int n = 0; n < 4; ++n){
    int col = n0 + wc + n*16 + fr;
    float bv = bias[col];
    #pragma unroll
    for (int m = 0; m < 4; ++m){
      #pragma unroll
      for (int q = 0; q < 4; ++q){
        int row = m0 + wr + m*16 + r4 + q;
        C[(size_t)row * GN + col] = f2bf(acc[m][n][q] + bv);
      }
    }
  }
}

// --------------------------------------------------- GRU chunk body
// R8: TAG-IN-DATA h exchange. h stored as u32 col-pairs; bit0 of each bf16 is
// a step-parity tag (h loses 1 mantissa bit). Rolling 65 slots: slot(t)=t%65;
// 65 odd => stale occupant (t-65) always has opposite parity. Producer: one
// relaxed agent atomic u32 store per thread — NO drain, NO flag. Consumer:
// batch-load 32 u64 fragments (uncached atomic), parity-check, reload pending
// only. Detect = one LLC hop; the poll IS the load. t==0 skips loads (h=0).
__device__ __forceinline__ void gru_chunk(
    const u16* __restrict__ gx, const u16* __restrict__ Whh, const float* __restrict__ bhh,
    u16* hbuf, u16* h1c, float* hstate, int base,
    int bl, u16* Ws, float* part, u16* hlds, float* bsh)
{
  int tid = threadIdx.x, lane = tid & 63, w = tid >> 6;
  int g = bl >> 6, wg = bl & 63;
  int c0 = wg * 16, rb0 = g * 32;
  for (int ch = tid; ch < 48 * 128; ch += 256){
    int r = ch >> 7, o = ch & 127;
    const u16* src = Whh + (size_t)((r >> 4) * HH + c0 + (r & 15)) * HH + o * 8;
    *reinterpret_cast<int4*>(&Ws[r * 1032 + o * 8]) = *reinterpret_cast<const int4*>(src);
  }
  if (tid < 48) bsh[tid] = bhh[(tid >> 4) * HH + c0 + (tid & 15)];
  __syncthreads();
  int b2 = tid >> 4, j = tid & 15;
  int fr = lane & 15, klo = (lane >> 4) * 8, kw = w * 256;
  const u16* gxp0 = gx + (size_t)(rb0 + b2) * TC * GN + c0 + j;
  const u16* gxp1 = gx + (size_t)(rb0 + 16 + b2) * TC * GN + c0 + j;
  float ho0 = hstate[(size_t)(rb0 + b2) * HH + c0 + j];
  float ho1 = hstate[(size_t)(rb0 + 16 + b2) * HH + c0 + j];
  int lnD = (b2 >> 2) * 16 + j, regD = b2 & 3; // D map: col=lane&15,row=(lane>>4)*4+reg
  float br = bhh[c0 + j];
  int rr = tid >> 3, pp = tid & 7;             // publish mapping: (row, col-pair)
  const int SLOTW = BB * HH / 2;               // u32 words per slot
  for (int tl = 0; tl < TC; ++tl){
    int t = base + tl;
    // gx loads are h-independent — issue first, overlap the poll
    float gxr0 = bf2f(gxp0[(size_t)tl * GN]);
    float gxz0 = bf2f(gxp0[(size_t)tl * GN + HH]);
    float gxn0 = bf2f(gxp0[(size_t)tl * GN + 2 * HH]);
    float gxr1 = bf2f(gxp1[(size_t)tl * GN]);
    float gxz1 = bf2f(gxp1[(size_t)tl * GN + HH]);
    float gxn1 = bf2f(gxp1[(size_t)tl * GN + 2 * HH]);
    bf16x8 af0[8], af1[8];
    if (t == 0){
      u64x2 z; z.x = 0; z.y = 0;
      #pragma unroll
      for (int ks = 0; ks < 8; ++ks){ af0[ks] = __builtin_bit_cast(bf16x8, z);
                                      af1[ks] = __builtin_bit_cast(bf16x8, z); }
    } else {
      const unsigned long long want = ((t - 1) & 1) ? PARMASK64 : 0ULL;
      const unsigned* rs = (const unsigned*)hbuf + (size_t)((t - 1) % NSLOT) * SLOTW;
      const unsigned* ba0 = rs + (size_t)(rb0 + fr) * 512 + ((kw + klo) >> 1);
      const unsigned* ba1 = ba0 + 16 * 512;
      unsigned long long vlo[2][8], vhi[2][8];
      #pragma unroll
      for (int ks = 0; ks < 8; ++ks){
        vlo[0][ks] = __hip_atomic_load((const unsigned long long*)(ba0 + ks*16),
                                       __ATOMIC_RELAXED, __HIP_MEMORY_SCOPE_AGENT);
        vhi[0][ks] = __hip_atomic_load((const unsigned long long*)(ba0 + ks*16 + 2),
                                       __ATOMIC_RELAXED, __HIP_MEMORY_SCOPE_AGENT);
        vlo[1][ks] = __hip_atomic_load((const unsigned long long*)(ba1 + ks*16),
                                       __ATOMIC_RELAXED, __HIP_MEMORY_SCOPE_AGENT);
        vhi[1][ks] = __hip_atomic_load((const unsigned long long*)(ba1 + ks*16 + 2),
                                       __ATOMIC_RELAXED, __HIP_MEMORY_SCOPE_AGENT);
      }
      for (;;){
        unsigned pend = 0;
        #pragma unroll
        for (int a = 0; a < 2; ++a)
          #pragma unroll
          for (int ks = 0; ks < 8; ++ks){
            if ((vlo[a][ks] & PARMASK64) != want) pend |= 1u << (a*8 + ks);
            if ((vhi[a][ks] & PARMASK64) != want) pend |= 1u << (16 + a*8 + ks);
          }
        if (__all((int)(pend == 0u))) break;
        #pragma unroll
        for (int a = 0; a < 2; ++a)
          #pragma unroll
          for (int ks = 0; ks < 8; ++ks){
            const unsigned* bb = (a ? ba1 : ba0) + ks*16;
            if (pend & (1u << (a*8 + ks)))
              vlo[a][ks] = __hip_atomic_load((const unsigned long long*)bb,
                                             __ATOMIC_RELAXED, __HIP_MEMORY_SCOPE_AGENT);
            if (pend & (1u << (16 + a*8 + ks)))
              vhi[a][ks] = __hip_atomic_load((const unsigned long long*)(bb + 2),
                                             __ATOMIC_RELAXED, __HIP_MEMORY_SCOPE_AGENT);
          }
      }
      #pragma unroll
      for (int ks = 0; ks < 8; ++ks){
        u64x2 p0; p0.x = vlo[0][ks] & KEEPMASK64; p0.y = vhi[0][ks] & KEEPMASK64;
        af0[ks] = __builtin_bit_cast(bf16x8, p0);
        u64x2 p1; p1.x = vlo[1][ks] & KEEPMASK64; p1.y = vhi[1][ks] & KEEPMASK64;
        af1[ks] = __builtin_bit_cast(bf16x8, p1);
      }
    }
    f32x4 acc[2][3] = {};
    #pragma unroll
    for (int ks = 0; ks < 8; ++ks){
      int kk = kw + ks * 32 + klo;
      bf16x8 w0 = *reinterpret_cast<const bf16x8*>(&Ws[(      fr) * 1032 + kk]);
      bf16x8 w1 = *reinterpret_cast<const bf16x8*>(&Ws[(16 + fr) * 1032 + kk]);
      bf16x8 w2 = *reinterpret_cast<const bf16x8*>(&Ws[(32 + fr) * 1032 + kk]);
      acc[0][0] = __builtin_amdgcn_mfma_f32_16x16x32_bf16(af0[ks], w0, acc[0][0], 0, 0, 0);
      acc[0][1] = __builtin_amdgcn_mfma_f32_16x16x32_bf16(af0[ks], w1, acc[0][1], 0, 0, 0);
      acc[0][2] = __builtin_amdgcn_mfma_f32_16x16x32_bf16(af0[ks], w2, acc[0][2], 0, 0, 0);
      acc[1][0] = __builtin_amdgcn_mfma_f32_16x16x32_bf16(af1[ks], w0, acc[1][0], 0, 0, 0);
      acc[1][1] = __builtin_amdgcn_mfma_f32_16x16x32_bf16(af1[ks], w1, acc[1][1], 0, 0, 0);
      acc[1][2] = __builtin_amdgcn_mfma_f32_16x16x32_bf16(af1[ks], w2, acc[1][2], 0, 0, 0);
    }
    #pragma unroll
    for (int at = 0; at < 2; ++at)
      #pragma unroll
      for (int gt = 0; gt < 3; ++gt)
        *reinterpret_cast<f32x4*>(&part[((w*6 + at*3 + gt)*64 + lane)*4]) = acc[at][gt];
    __syncthreads();
    float gh[2][3];
    #pragma unroll
    for (int at = 0; at < 2; ++at)
      #pragma unroll
      for (int gt = 0; gt < 3; ++gt){
        float s = 0.f;
        #pragma unroll
        for (int ww = 0; ww < 4; ++ww)
          s += part[((ww*6 + at*3 + gt)*64 + lnD)*4 + regD];
        gh[at][gt] = s;
      }
    float bz = bsh[16 + j], bn2 = bsh[32 + j];
    float r0 = __builtin_amdgcn_rcpf(1.f + __expf(-(gxr0 + gh[0][0] + br)));
    float z0 = __builtin_amdgcn_rcpf(1.f + __expf(-(gxz0 + gh[0][1] + bz)));
    float nx0 = gxn0 + r0 * (gh[0][2] + bn2);
    float n0 = 1.f - 2.f * __builtin_amdgcn_rcpf(__expf(2.f * nx0) + 1.f);
    float hn0 = (1.f - z0) * n0 + z0 * ho0;
    float r1 = __builtin_amdgcn_rcpf(1.f + __expf(-(gxr1 + gh[1][0] + br)));
    float z1 = __builtin_amdgcn_rcpf(1.f + __expf(-(gxz1 + gh[1][1] + bz)));
    float nx1 = gxn1 + r1 * (gh[1][2] + bn2);
    float n1 = 1.f - 2.f * __builtin_amdgcn_rcpf(__expf(2.f * nx1) + 1.f);
    float hn1 = (1.f - z1) * n1 + z1 * ho1;
    ho0 = hn0; ho1 = hn1;                        // f32 self-path
    u16 hb0 = f2bf(hn0), hb1 = f2bf(hn1);
    // stage for col-pair packing (pre-pack barrier also guards `part` reuse)
    hlds[b2 * 16 + j] = hb0;
    hlds[(16 + b2) * 16 + j] = hb1;
    __syncthreads();
    unsigned pk = (unsigned)hlds[rr*16 + pp*2] | ((unsigned)hlds[rr*16 + pp*2 + 1] << 16);
    pk = (pk & 0xFFFEFFFEu) | ((t & 1) ? 0x00010001u : 0u);
    __hip_atomic_store((unsigned*)hbuf + (size_t)(t % NSLOT) * SLOTW
                         + (size_t)(rb0 + rr) * 512 + (c0 >> 1) + pp,
                       pk, __ATOMIC_RELAXED, __HIP_MEMORY_SCOPE_AGENT);
    // non-critical stores after publish (cross-dispatch consumers only)
    if (h1c){
      h1c[((size_t)(rb0 + b2) * TC + tl) * HH + c0 + j] = hb0;
      h1c[((size_t)(rb0 + 16 + b2) * TC + tl) * HH + c0 + j] = hb1;
    }
    if (tl == TC - 1){
      hstate[(size_t)(rb0 + b2) * HH + c0 + j] = hn0;
      hstate[(size_t)(rb0 + 16 + b2) * HH + c0 + j] = hn1;
    }
  }
}

// --------- fused dispatch: 128 WGs role A (L0 chunk c) || 128 WGs role B (L1 chunk c-1)
__global__ __launch_bounds__(256, 1) void gru_fused(
    const u16* gxA, const u16* WhhA, const float* bhhA, u16* hbufA,
    u16* h1cA, float* hstA, int baseA,
    const u16* gxB, const u16* WhhB, const float* bhhB, u16* hbufB,
    float* hstB, int baseB)
{
  __shared__ u16 Ws[48 * 1032];      // 99KB
  __shared__ float part[4*6*64*4];   // 24KB
  __shared__ u16 hlds[32 * 16];      // 1KB pack staging
  __shared__ float bsh[48];
  int blk = blockIdx.x;
  if (blk < 128){
    if (!gxA) return;
    gru_chunk(gxA, WhhA, bhhA, hbufA, h1cA, hstA, baseA, blk, Ws, part, hlds, bsh);
  } else {
    if (!gxB) return;
    gru_chunk(gxB, WhhB, bhhB, hbufB, nullptr, hstB, baseB, blk - 128, Ws, part, hlds, bsh);
  }
}

// ---------------------------------------------------- x_projected[:, -1, :] (f32)
__global__ __launch_bounds__(256) void xproj_kernel(const float* __restrict__ x,
    const float* __restrict__ wproj, const float* __restrict__ bproj, float* __restrict__ xp){
  __shared__ float xs[II];
  int b = blockIdx.x >> 2, n0 = (blockIdx.x & 3) << 8;
  const float* xrow = x + ((size_t)b * TT + (TT - 1)) * II;
  for (int i = threadIdx.x; i < II; i += 256) xs[i] = xrow[i];
  __syncthreads();
  int n = n0 + threadIdx.x;
  const float* wrow = wproj + (size_t)n * II;
  float s = 0.f;
  #pragma unroll 4
  for (int k = 0; k < II; k += 4){
    float4 w4 = *reinterpret_cast<const float4*>(&wrow[k]);
    s += xs[k]*w4.x + xs[k+1]*w4.y + xs[k+2]*w4.z + xs[k+3]*w4.w;
  }
  xp[(size_t)b * HH + n] = s + bproj[n];
}

// ------------------------------------- residual + BN(inference) + out GEMM (f32)
__global__ __launch_bounds__(256) void final_kernel(const float* __restrict__ xp,
    const float* __restrict__ hl, const float* __restrict__ gamma, const float* __restrict__ beta,
    const float* __restrict__ mean, const float* __restrict__ var,
    const float* __restrict__ wout, const float* __restrict__ bout, float* __restrict__ out){
  __shared__ float bn[2 * HH];
  int b0 = blockIdx.x * 2;
  for (int i = threadIdx.x; i < 2 * HH; i += 256){
    int bb = i >> 10, jj = i & (HH - 1);
    float res = xp[(size_t)(b0 + bb) * HH + jj] + hl[(size_t)(b0 + bb) * HH + jj];
    bn[i] = (res - mean[jj]) * rsqrtf(var[jj] + 1e-5f) * gamma[jj] + beta[jj];
  }
  __syncthreads();
  int bb = threadIdx.x >> 7, o = threadIdx.x & (OO - 1);
  const float* wrow = wout + (size_t)o * HH;
  const float* bnrow = bn + bb * HH;
  float s = 0.f;
  #pragma unroll 4
  for (int k = 0; k < HH; k += 4){
    float4 w4 = *reinterpret_cast<const float4*>(&wrow[k]);
    s += bnrow[k]*w4.x + bnrow[k+1]*w4.y + bnrow[k+2]*w4.z + bnrow[k+3]*w4.w;
  }
  out[(size_t)(b0 + bb) * OO + o] = s + bout[o];
}

extern "C" void kernel_launch(void* const* d_in, const int* in_sizes, int n_in,
                              void* d_out, int out_size, void* d_ws, size_t ws_size,
                              hipStream_t stream) {
  const float* x      = (const float*)d_in[0];
  const float* w_proj = (const float*)d_in[1];
  const float* b_proj = (const float*)d_in[2];
  const float* w_ih0  = (const float*)d_in[3];
  const float* w_hh0  = (const float*)d_in[4];
  const float* b_ih0  = (const float*)d_in[5];
  const float* b_hh0  = (const float*)d_in[6];
  const float* w_ih1  = (const float*)d_in[7];
  const float* w_hh1  = (const float*)d_in[8];
  const float* b_ih1  = (const float*)d_in[9];
  const float* b_hh1  = (const float*)d_in[10];
  const float* gamma  = (const float*)d_in[11];
  const float* beta   = (const float*)d_in[12];
  const float* mean   = (const float*)d_in[13];
  const float* var    = (const float*)d_in[14];
  const float* w_out  = (const float*)d_in[15];
  const float* b_out  = (const float*)d_in[16];
  float* out = (float*)d_out;

  char* ws = (char*)d_ws;
  size_t off = 0;
  float* hst0  = (float*)(ws + off); off += (size_t)BB*HH*4;               // 256 KB
  float* hst1  = (float*)(ws + off); off += (size_t)BB*HH*4;
  size_t zeroA = off;                                                      // hstates
  u16* hbuf0   = (u16*)(ws + off);   off += (size_t)NSLOT*BB*HH*2;         // 8.5 MB
  u16* hbuf1   = (u16*)(ws + off);   off += (size_t)NSLOT*BB*HH*2;
  float* xproj = (float*)(ws + off); off += (size_t)BB*HH*4;
  u16* xck     = (u16*)(ws + off);   off += (size_t)BB*TC*II*2;            // 4.2 MB
  u16* h1c     = (u16*)(ws + off);   off += (size_t)BB*TC*HH*2;            // 8.4 MB
  u16* wih0b   = (u16*)(ws + off);   off += (size_t)3*HH*II*2;             // 3.1 MB
  u16* whh0b   = (u16*)(ws + off);   off += (size_t)3*HH*HH*2;             // 6.3 MB
  u16* wih1b   = (u16*)(ws + off);   off += (size_t)3*HH*HH*2;
  u16* whh1b   = (u16*)(ws + off);   off += (size_t)3*HH*HH*2;
  u16* gxc0    = (u16*)(ws + off);   off += (size_t)BB*TC*3*HH*2;          // 25.2 MB
  u16* gxc1    = (u16*)(ws + off);   off += (size_t)BB*TC*3*HH*2;
  // total ~104 MB

  hipMemsetAsync(d_ws, 0, zeroA, stream);                    // hstates = h(-1) = 0
  hinit_kernel<<<2048, 256, 0, stream>>>((unsigned long long*)hbuf0,
                                         (unsigned long long*)hbuf1);

  cvt_kernel<<<512, 256, 0, stream>>>(w_ih0, wih0b, (3*HH*II) / 4);
  cvt_kernel<<<512, 256, 0, stream>>>(w_hh0, whh0b, (3*HH*HH) / 4);
  cvt_kernel<<<512, 256, 0, stream>>>(w_ih1, wih1b, (3*HH*HH) / 4);
  cvt_kernel<<<512, 256, 0, stream>>>(w_hh1, whh1b, (3*HH*HH) / 4);

  xproj_kernel<<<256, 256, 0, stream>>>(x, w_proj, b_proj, xproj);

  dim3 ggrid(BB * TC / 128, GN / 128);           // (32, 24)

  // prologue: L0 chunk 0 alone
  cvtx_chunk<<<1024, 256, 0, stream>>>(x, xck, 0);
  gemm_bias<II><<<ggrid, 256, 0, stream>>>(xck, wih0b, b_ih0, gxc0);
  gru_fused<<<256, 256, 0, stream>>>(gxc0, whh0b, b_hh0, hbuf0, h1c, hst0, 0,
                                     nullptr, whh1b, b_hh1, hbuf1, hst1, 0);
  // steady state: L0(k) || L1(k-1)
  for (int k = 1; k < NCH; ++k){
    gemm_bias<HH><<<ggrid, 256, 0, stream>>>(h1c, wih1b, b_ih1, gxc1);   // gx1(k-1)
    cvtx_chunk<<<1024, 256, 0, stream>>>(x, xck, k * TC);
    gemm_bias<II><<<ggrid, 256, 0, stream>>>(xck, wih0b, b_ih0, gxc0);   // gx0(k)
    gru_fused<<<256, 256, 0, stream>>>(gxc0, whh0b, b_hh0, hbuf0, h1c, hst0, k*TC,
                                       gxc1, whh1b, b_hh1, hbuf1, hst1, (k-1)*TC);
  }
  // epilogue: L1 chunk 7 alone
  gemm_bias<HH><<<ggrid, 256, 0, stream>>>(h1c, wih1b, b_ih1, gxc1);
  gru_fused<<<256, 256, 0, stream>>>(nullptr, whh0b, b_hh0, hbuf0, h1c, hst0, 0,
                                     gxc1, whh1b, b_hh1, hbuf1, hst1, (NCH-1)*TC);

  final_kernel<<<BB / 2, 256, 0, stream>>>(xproj, hst1, gamma, beta, mean, var, w_out, b_out, out);
}